// Round 1
// 233.690 us; speedup vs baseline: 1.0734x; 1.0734x over previous
//
#include <hip/hip_runtime.h>
#include <math.h>

// GCN 4-layer, N=100k, E=3.2M. Round 13:
//  - k_agg2mv/k_agg3 gather restructure: branchless phantom-padded 8-deep
//    batch (first 64 edges unconditional; invalid slots -> zeroed phantom row
//    at index N). Mean degree 32 meant the old 4-deep loop never ran for
//    ~half the nodes (gather went 1-deep serial). Now 8 loads/lane in flight
//    for every node.
//  - fp16 pairwise-tree accumulate (v_pk_add_f16, depth 2) before f32
//    convert: ~3x VALU cut in the gather inner loop (was scalar cvt+add).
//  - ss region +64 ints slack so padded slots load safely (values discarded
//    via cndmask, never used as addresses). Gh/Gh3 +32 halves phantom row,
//    zeroed in k_initcur.
// Identities: norm factorizes (dinv pre/post scale); matmul commutes with
// segment-sum, so layers 1/4 aggregate scalars.

#define BLK 256
#define PBLK 1024         // k_place threads
#define BBLK 512          // k_build threads
#define NBLK 256          // edge-pass blocks
#define MAXCHUNK 12544    // >= ceil(E/NBLK)=12500
#define CAP 5120          // per-bucket segment capacity (mean 4096, +16 sigma)

typedef _Float16 half8 __attribute__((ext_vector_type(8)));

// ---- CSR build ----------------------------------------------------------

__global__ void k_initcur(int* __restrict__ cursor, int NB,
                          _Float16* __restrict__ ph1, _Float16* __restrict__ ph2) {
    int b = blockIdx.x * blockDim.x + threadIdx.x;
    if (b < NB) cursor[b] = b * CAP;
    if (b < 32) { ph1[b] = (_Float16)0.f; ph2[b] = (_Float16)0.f; }
}

// per-block LDS multisplit + coalesced flush into segmented bkt regions
__global__ void __launch_bounds__(PBLK) k_place(
        const int* __restrict__ src, const int* __restrict__ dst,
        int* __restrict__ cursor, int* __restrict__ bkt, int E, int chunk) {
    __shared__ int hist[788];          // counts, then wbase after reservation
    __shared__ int lofs[788];
    __shared__ int lcur[788];
    __shared__ int tmp[PBLK];
    __shared__ int stage[MAXCHUNK];
    int t = threadIdx.x;
    int b0 = blockIdx.x * chunk;
    int b1 = min(E, b0 + chunk);
    int n = b1 - b0;
    if (t < 788) hist[t] = 0;
    __syncthreads();
    for (int k = b0 + t; k < b1; k += PBLK) atomicAdd(&hist[dst[k] >> 7], 1);
    __syncthreads();
    int v = (t < 788) ? hist[t] : 0;
    tmp[t] = v;
    __syncthreads();
    for (int o = 1; o < PBLK; o <<= 1) {
        int a = (t >= o) ? tmp[t - o] : 0;
        __syncthreads();
        tmp[t] += a;
        __syncthreads();
    }
    int ex = tmp[t] - v;
    if (t < 788) { lofs[t] = ex; lcur[t] = ex; }
    __syncthreads();
    if (t < 782) {
        int c = hist[t];
        hist[t] = c ? atomicAdd(&cursor[t], c) : 0;   // segmented reservation
    }
    __syncthreads();
    for (int k = b0 + t; k < b1; k += PBLK) {
        int d = dst[k], s = src[k];
        int b = d >> 7;
        int p = atomicAdd(&lcur[b], 1);
        stage[p] = s | ((d & 127) << 17);
    }
    __syncthreads();
    for (int k = t; k < n; k += PBLK) {
        int lo = 0, hi = 781;
        while (lo < hi) {
            int mid = (lo + hi + 1) >> 1;
            if (lofs[mid] <= k) lo = mid; else hi = mid - 1;
        }
        int pos = hist[lo] + (k - lofs[lo]);
        if (pos < (lo + 1) * CAP) bkt[pos] = stage[k];   // clamp (never hits)
    }
}

// block per bucket -> 1024-bin (node, src>>14) hist + in-place scan, LDS
// scatter, linear flush; writes rs2 (beg,len), dinv, sa
__global__ void __launch_bounds__(BBLK) k_build(
        const int* __restrict__ cursor, const int* __restrict__ bkt,
        const float* __restrict__ x,
        uint2* __restrict__ rs2, int* __restrict__ ss,
        float* __restrict__ dinv, float* __restrict__ sa, int N) {
    __shared__ int cnt[1024], lofs[1024], lcur[1024];
    __shared__ int tmp[BBLK];
    __shared__ int stg[CAP];
    int b = blockIdx.x, t = threadIdx.x;
    int node_base = b << 7;
    int gb = b * CAP;
    int sz = min(cursor[b] - gb, CAP);
    for (int i = t; i < 1024; i += BBLK) cnt[i] = 0;
    __syncthreads();
    const int* q = bkt + gb;
    for (int k = t; k < sz; k += BBLK) {
        int v = q[k];
        int bin = (((v >> 17) & 127) << 3) | ((v & 0x1FFFF) >> 14);
        atomicAdd(&cnt[bin], 1);
    }
    __syncthreads();
    // in-place scan of 1024 bins, 2 per thread
    int vals[2];
    int sum = 0;
    int i0 = t << 1;
    #pragma unroll
    for (int r = 0; r < 2; ++r) { vals[r] = cnt[i0 + r]; sum += vals[r]; }
    tmp[t] = sum;
    __syncthreads();
    for (int o = 1; o < BBLK; o <<= 1) {
        int a = (t >= o) ? tmp[t - o] : 0;
        __syncthreads();
        tmp[t] += a;
        __syncthreads();
    }
    int run = tmp[t] - sum;
    #pragma unroll
    for (int r = 0; r < 2; ++r) {
        int c = vals[r];
        lofs[i0 + r] = run;
        lcur[i0 + r] = run;
        run += c;
    }
    __syncthreads();
    if (t < 128) {
        int i = node_base + t;
        if (i < N) {
            int beg = lofs[t << 3];
            int end = (t < 127) ? lofs[(t + 1) << 3] : sz;
            int len = end - beg;
            rs2[i] = make_uint2((unsigned)(gb + beg), (unsigned)len);
            float d = rsqrtf((float)len + 1.0f);
            dinv[i] = d;
            sa[i] = x[i] * d;
        }
    }
    __syncthreads();
    for (int k = t; k < sz; k += BBLK) {
        int v = q[k];
        int bin = (((v >> 17) & 127) << 3) | ((v & 0x1FFFF) >> 14);
        int pos = atomicAdd(&lcur[bin], 1);
        stg[pos] = v & 0x1FFFF;
    }
    __syncthreads();
    for (int k = t; k < sz; k += BBLK) ss[gb + k] = stg[k];
}

// ---- layers -------------------------------------------------------------

// layer 1 + fused layer-2 matvec: scalar gather -> F1 (lane=feature) ->
// Gh[i,l] = dinv_i * sum_k F1_k * Wmid[k][l], via 32 shuffles
__global__ void k_l1aggG(const uint2* __restrict__ rs2, const int* __restrict__ ss,
                         const float* __restrict__ sa, const float* __restrict__ dinv,
                         const float* __restrict__ Win, const float* __restrict__ bin,
                         const float* __restrict__ Wmid, _Float16* __restrict__ Gh, int N) {
    int t = blockIdx.x * blockDim.x + threadIdx.x;
    int i = t >> 5, l = t & 31;
    if (i >= N) return;
    float wcol[32];
    #pragma unroll
    for (int k = 0; k < 32; ++k) wcol[k] = Wmid[k * 32 + l];
    uint2 r = rs2[i];
    int beg = (int)r.x, end = (int)(r.x + r.y);
    float s = 0.f;
    for (int e = beg + l; e < end; e += 32) s += sa[ss[e]];
    #pragma unroll
    for (int m = 16; m; m >>= 1) s += __shfl_xor(s, m, 32);
    float d = dinv[i];
    float h = d * (s + sa[i]);
    float F = h * Win[l] + bin[l];
    F = F > 0.f ? F : 0.f;
    float g = 0.f;
    #pragma unroll
    for (int k = 0; k < 32; ++k) g += __shfl(F, k, 32) * wcol[k];
    Gh[t] = (_Float16)(g * d);
}

// layer-2 aggregate + fused layer-3 matvec: branchless phantom-padded 8-deep
// gather of Gh rows -> fp16 pk_add tree -> relu F rows (LDS) -> block 32x32
// matvec -> Gh3 (fp16)
__global__ void __launch_bounds__(256) k_agg2mv(
        const uint2* __restrict__ rs2, const int* __restrict__ ss,
        const half8* __restrict__ G8, const float* __restrict__ dinv,
        const float* __restrict__ b, const float* __restrict__ Wmid,
        _Float16* __restrict__ Gh3, int N) {
    __shared__ float sW[1024];
    __shared__ float sF[8][33];
    __shared__ float sdv[8];
    int t = threadIdx.x;
    #pragma unroll
    for (int r = 0; r < 4; ++r) sW[r * 256 + t] = Wmid[r * 256 + t];
    int tg = blockIdx.x * blockDim.x + t;
    int g = tg >> 5;
    int lane = t & 31, sub = lane >> 2, fl = lane & 3;
    int grp = t >> 5;
    bool act = (g < N);
    float acc[8];
    #pragma unroll
    for (int j = 0; j < 8; ++j) acc[j] = 0.f;
    if (act) {
        uint2 r = rs2[g];
        int beg = (int)r.x;
        int len = (int)r.y;
        int end = beg + len;
        // first 64 edges: unconditional 8-deep batch; invalid slots -> phantom
        int idx[8];
        #pragma unroll
        for (int rr = 0; rr < 8; ++rr) {
            int slot = beg + sub + 8 * rr;
            int ssv = ss[slot];               // always safe (ss +64 slack)
            idx[rr] = (slot < end) ? ssv : N; // N = zeroed phantom row
        }
        half8 v[8];
        #pragma unroll
        for (int rr = 0; rr < 8; ++rr) v[rr] = G8[(long long)idx[rr] * 4 + fl];
        half8 s01 = v[0] + v[1];
        half8 s23 = v[2] + v[3];
        half8 s45 = v[4] + v[5];
        half8 s67 = v[6] + v[7];
        half8 a0 = s01 + s23;
        half8 a1 = s45 + s67;
        #pragma unroll
        for (int j = 0; j < 8; ++j) acc[j] = (float)a0[j] + (float)a1[j];
        if (sub == 0) {
            half8 sv = G8[(long long)g * 4 + fl];   // self term
            #pragma unroll
            for (int j = 0; j < 8; ++j) acc[j] += (float)sv[j];
        }
        // rare deep-degree tail (deg > 64)
        for (int e = beg + 64 + sub; e < end; e += 8) {
            half8 vv = G8[(long long)ss[e] * 4 + fl];
            #pragma unroll
            for (int j = 0; j < 8; ++j) acc[j] += (float)vv[j];
        }
    }
    #pragma unroll
    for (int j = 0; j < 8; ++j) {
        acc[j] += __shfl_xor(acc[j], 4);
        acc[j] += __shfl_xor(acc[j], 8);
        acc[j] += __shfl_xor(acc[j], 16);
    }
    if (act && sub == 0) {
        float d = dinv[g];
        if (fl == 0) sdv[grp] = d;
        #pragma unroll
        for (int j = 0; j < 8; ++j) {
            float v = d * acc[j] + b[fl * 8 + j];
            sF[grp][fl * 8 + j] = v > 0.f ? v : 0.f;
        }
    }
    __syncthreads();
    // block matvec: node grp, output feature lane
    if (act) {
        float s = 0.f;
        #pragma unroll
        for (int k = 0; k < 32; ++k) s += sF[grp][k] * sW[k * 32 + lane];
        Gh3[(long long)g * 32 + lane] = (_Float16)(s * sdv[grp]);
    }
}

// layer-3 aggregate + fused W_out dot: same gather structure; writes only sa[i]
__global__ void __launch_bounds__(256) k_agg3(
        const uint2* __restrict__ rs2, const int* __restrict__ ss,
        const half8* __restrict__ G8, const float* __restrict__ dinv,
        const float* __restrict__ b, const float* __restrict__ Wout,
        float* __restrict__ sa, int N) {
    int t = blockIdx.x * blockDim.x + threadIdx.x;
    int g = t >> 5;
    if (g >= N) return;
    int lane = t & 31, sub = lane >> 2, fl = lane & 3;
    uint2 r = rs2[g];
    int beg = (int)r.x;
    int len = (int)r.y;
    int end = beg + len;
    float acc[8];
    int idx[8];
    #pragma unroll
    for (int rr = 0; rr < 8; ++rr) {
        int slot = beg + sub + 8 * rr;
        int ssv = ss[slot];               // always safe (ss +64 slack)
        idx[rr] = (slot < end) ? ssv : N; // N = zeroed phantom row
    }
    half8 v[8];
    #pragma unroll
    for (int rr = 0; rr < 8; ++rr) v[rr] = G8[(long long)idx[rr] * 4 + fl];
    half8 s01 = v[0] + v[1];
    half8 s23 = v[2] + v[3];
    half8 s45 = v[4] + v[5];
    half8 s67 = v[6] + v[7];
    half8 a0 = s01 + s23;
    half8 a1 = s45 + s67;
    #pragma unroll
    for (int j = 0; j < 8; ++j) acc[j] = (float)a0[j] + (float)a1[j];
    if (sub == 0) {
        half8 sv = G8[(long long)g * 4 + fl];   // self term
        #pragma unroll
        for (int j = 0; j < 8; ++j) acc[j] += (float)sv[j];
    }
    for (int e = beg + 64 + sub; e < end; e += 8) {
        half8 vv = G8[(long long)ss[e] * 4 + fl];
        #pragma unroll
        for (int j = 0; j < 8; ++j) acc[j] += (float)vv[j];
    }
    #pragma unroll
    for (int j = 0; j < 8; ++j) {
        acc[j] += __shfl_xor(acc[j], 4);
        acc[j] += __shfl_xor(acc[j], 8);
        acc[j] += __shfl_xor(acc[j], 16);
    }
    if (sub == 0) {
        float d = dinv[g];
        float p = 0.f;
        #pragma unroll
        for (int j = 0; j < 8; ++j) {
            float v = d * acc[j] + b[fl * 8 + j];
            v = v > 0.f ? v : 0.f;
            p += v * Wout[fl * 8 + j];
        }
        p += __shfl_xor(p, 1, 32);
        p += __shfl_xor(p, 2, 32);
        if (fl == 0) sa[g] = p * d;
    }
}

// layer 4: scalar gather-reduce + sigmoid, fused
__global__ void k_final_agg(const uint2* __restrict__ rs2, const int* __restrict__ ss,
                            const float* __restrict__ sa, const float* __restrict__ dinv,
                            const float* __restrict__ bout, float* __restrict__ out, int N) {
    int t = blockIdx.x * blockDim.x + threadIdx.x;
    int i = t >> 5, l = t & 31;
    if (i >= N) return;
    uint2 r = rs2[i];
    int beg = (int)r.x, end = (int)(r.x + r.y);
    float s = 0.f;
    for (int e = beg + l; e < end; e += 32) s += sa[ss[e]];
    #pragma unroll
    for (int m = 16; m; m >>= 1) s += __shfl_xor(s, m, 32);
    if (l == 0) {
        float z = dinv[i] * (s + sa[i]) + bout[0];
        out[i] = 1.0f / (1.0f + expf(-z));
    }
}

extern "C" void kernel_launch(void* const* d_in, const int* in_sizes, int n_in,
                              void* d_out, int out_size, void* d_ws, size_t ws_size,
                              hipStream_t stream) {
    const float* x    = (const float*)d_in[0];
    const int*   ei   = (const int*)  d_in[1];
    const float* Win  = (const float*)d_in[2];
    const float* bin  = (const float*)d_in[3];
    const float* Wmid = (const float*)d_in[4];
    const float* bmid = (const float*)d_in[5];
    const float* Wout = (const float*)d_in[6];
    const float* bout = (const float*)d_in[7];
    float* out = (float*)d_out;

    int N = in_sizes[0];
    int E = in_sizes[1] / 2;
    const int* src = ei;
    const int* dst = ei + E;

    int NB = (N + 127) >> 7;                       // 782 buckets of 128 nodes
    int chunk = (E + NBLK - 1) / NBLK;             // 12500

    // workspace layout (all regions disjoint; ~47MB)
    int* cursor = (int*)d_ws;                      // 1024
    uint2* rs2  = (uint2*)(cursor + 1024);         // N+8
    int* ss     = (int*)(rs2 + N + 8);             // NB*CAP + 64 slack
    float* dinv = (float*)(ss + (size_t)NB * CAP + 64); // N
    float* sa   = dinv + N;                        // N
    _Float16* Gh  = (_Float16*)(sa + N);           // 32N + 32 (phantom row) fp16
    _Float16* Gh3 = Gh + 32 * (size_t)N + 32;      // 32N + 32 fp16
    int* bkt    = (int*)(Gh3 + 32 * (size_t)N + 32); // NB*CAP

    int NT   = N * 32;
    int gN32 = (NT + BLK - 1) / BLK;

    // CSR build: init cursors + zero phantom rows -> LDS multisplit place ->
    // per-bucket sort
    k_initcur<<<(NB + BLK - 1) / BLK, BLK, 0, stream>>>(
        cursor, NB, Gh + 32 * (size_t)N, Gh3 + 32 * (size_t)N);
    k_place<<<NBLK, PBLK, 0, stream>>>(src, dst, cursor, bkt, E, chunk);
    k_build<<<NB, BBLK, 0, stream>>>(cursor, bkt, x, rs2, ss, dinv, sa, N);

    // layer 1 (+ fused layer-2 matvec) -> Gh
    k_l1aggG<<<gN32, BLK, 0, stream>>>(rs2, ss, sa, dinv, Win, bin, Wmid, Gh, N);

    // layer 2 aggregate (+ fused layer-3 matvec) -> Gh3
    k_agg2mv<<<gN32, BLK, 0, stream>>>(rs2, ss, (const half8*)Gh, dinv, bmid,
                                       Wmid, Gh3, N);

    // layer 3 aggregate (+ fused W_out dot) -> sa
    k_agg3<<<gN32, BLK, 0, stream>>>(rs2, ss, (const half8*)Gh3, dinv, bmid,
                                     Wout, sa, N);

    // layer 4: scalar aggregate + sigmoid
    k_final_agg<<<gN32, BLK, 0, stream>>>(rs2, ss, sa, dinv, bout, out, N);
}

// Round 2
// 227.608 us; speedup vs baseline: 1.1021x; 1.0267x over previous
//
#include <hip/hip_runtime.h>
#include <math.h>

// GCN 4-layer, N=100k, E=3.2M. Round 14:
//  - Gh/Gh3 feature tables fp16 -> fp8 e4m3 (x64 pre-scale; /64 folded into
//    epilogue). Rows 64B -> 32B: table 6.4MB -> 3.2MB fits per-XCD L2 (4MB),
//    halves gather miss bytes. Random-src gather was the L2-miss-bound
//    bottleneck (round-0 FETCH 98MB vs 211MB requested = 53% hit).
//  - Accumulate in f32 via v_cvt_pk_f32_fp8 + packed f32 adds (f32x2):
//    removes r13's fp16-tree accumulation error (offsets fp8 quant error),
//    and is fewer VALU ops (8/edge/lane vs ~11).
//  - Keep 8-deep branchless phantom-padded gather (phantom row = index N,
//    zeroed; ss has +64 slack so padded slots load safely).
// Identities: norm factorizes (dinv pre/post scale); matmul commutes with
// segment-sum, so layers 1/4 aggregate scalars.

#define BLK 256
#define PBLK 1024         // k_place threads
#define BBLK 512          // k_build threads
#define NBLK 256          // edge-pass blocks
#define MAXCHUNK 12544    // >= ceil(E/NBLK)=12500
#define CAP 5120          // per-bucket segment capacity (mean 4096, +16 sigma)

#define FP8_SCALE 64.0f
#define FP8_INV   0.015625f

typedef float f32x2 __attribute__((ext_vector_type(2)));

// ---- CSR build ----------------------------------------------------------

__global__ void k_initcur(int* __restrict__ cursor, int NB,
                          int* __restrict__ ph1, int* __restrict__ ph2) {
    int b = blockIdx.x * blockDim.x + threadIdx.x;
    if (b < NB) cursor[b] = b * CAP;
    if (b < 8) { ph1[b] = 0; ph2[b] = 0; }   // zero 32B phantom rows
}

// per-block LDS multisplit + coalesced flush into segmented bkt regions
__global__ void __launch_bounds__(PBLK) k_place(
        const int* __restrict__ src, const int* __restrict__ dst,
        int* __restrict__ cursor, int* __restrict__ bkt, int E, int chunk) {
    __shared__ int hist[788];          // counts, then wbase after reservation
    __shared__ int lofs[788];
    __shared__ int lcur[788];
    __shared__ int tmp[PBLK];
    __shared__ int stage[MAXCHUNK];
    int t = threadIdx.x;
    int b0 = blockIdx.x * chunk;
    int b1 = min(E, b0 + chunk);
    int n = b1 - b0;
    if (t < 788) hist[t] = 0;
    __syncthreads();
    for (int k = b0 + t; k < b1; k += PBLK) atomicAdd(&hist[dst[k] >> 7], 1);
    __syncthreads();
    int v = (t < 788) ? hist[t] : 0;
    tmp[t] = v;
    __syncthreads();
    for (int o = 1; o < PBLK; o <<= 1) {
        int a = (t >= o) ? tmp[t - o] : 0;
        __syncthreads();
        tmp[t] += a;
        __syncthreads();
    }
    int ex = tmp[t] - v;
    if (t < 788) { lofs[t] = ex; lcur[t] = ex; }
    __syncthreads();
    if (t < 782) {
        int c = hist[t];
        hist[t] = c ? atomicAdd(&cursor[t], c) : 0;   // segmented reservation
    }
    __syncthreads();
    for (int k = b0 + t; k < b1; k += PBLK) {
        int d = dst[k], s = src[k];
        int b = d >> 7;
        int p = atomicAdd(&lcur[b], 1);
        stage[p] = s | ((d & 127) << 17);
    }
    __syncthreads();
    for (int k = t; k < n; k += PBLK) {
        int lo = 0, hi = 781;
        while (lo < hi) {
            int mid = (lo + hi + 1) >> 1;
            if (lofs[mid] <= k) lo = mid; else hi = mid - 1;
        }
        int pos = hist[lo] + (k - lofs[lo]);
        if (pos < (lo + 1) * CAP) bkt[pos] = stage[k];   // clamp (never hits)
    }
}

// block per bucket -> 1024-bin (node, src>>14) hist + in-place scan, LDS
// scatter, linear flush; writes rs2 (beg,len), dinv, sa
__global__ void __launch_bounds__(BBLK) k_build(
        const int* __restrict__ cursor, const int* __restrict__ bkt,
        const float* __restrict__ x,
        uint2* __restrict__ rs2, int* __restrict__ ss,
        float* __restrict__ dinv, float* __restrict__ sa, int N) {
    __shared__ int cnt[1024], lofs[1024], lcur[1024];
    __shared__ int tmp[BBLK];
    __shared__ int stg[CAP];
    int b = blockIdx.x, t = threadIdx.x;
    int node_base = b << 7;
    int gb = b * CAP;
    int sz = min(cursor[b] - gb, CAP);
    for (int i = t; i < 1024; i += BBLK) cnt[i] = 0;
    __syncthreads();
    const int* q = bkt + gb;
    for (int k = t; k < sz; k += BBLK) {
        int v = q[k];
        int bin = (((v >> 17) & 127) << 3) | ((v & 0x1FFFF) >> 14);
        atomicAdd(&cnt[bin], 1);
    }
    __syncthreads();
    // in-place scan of 1024 bins, 2 per thread
    int vals[2];
    int sum = 0;
    int i0 = t << 1;
    #pragma unroll
    for (int r = 0; r < 2; ++r) { vals[r] = cnt[i0 + r]; sum += vals[r]; }
    tmp[t] = sum;
    __syncthreads();
    for (int o = 1; o < BBLK; o <<= 1) {
        int a = (t >= o) ? tmp[t - o] : 0;
        __syncthreads();
        tmp[t] += a;
        __syncthreads();
    }
    int run = tmp[t] - sum;
    #pragma unroll
    for (int r = 0; r < 2; ++r) {
        int c = vals[r];
        lofs[i0 + r] = run;
        lcur[i0 + r] = run;
        run += c;
    }
    __syncthreads();
    if (t < 128) {
        int i = node_base + t;
        if (i < N) {
            int beg = lofs[t << 3];
            int end = (t < 127) ? lofs[(t + 1) << 3] : sz;
            int len = end - beg;
            rs2[i] = make_uint2((unsigned)(gb + beg), (unsigned)len);
            float d = rsqrtf((float)len + 1.0f);
            dinv[i] = d;
            sa[i] = x[i] * d;
        }
    }
    __syncthreads();
    for (int k = t; k < sz; k += BBLK) {
        int v = q[k];
        int bin = (((v >> 17) & 127) << 3) | ((v & 0x1FFFF) >> 14);
        int pos = atomicAdd(&lcur[bin], 1);
        stg[pos] = v & 0x1FFFF;
    }
    __syncthreads();
    for (int k = t; k < sz; k += BBLK) ss[gb + k] = stg[k];
}

// ---- layers -------------------------------------------------------------

// layer 1 + fused layer-2 matvec: scalar gather -> F1 (lane=feature) ->
// Gh[i,l] = 64 * dinv_i * sum_k F1_k * Wmid[k][l] (fp8), via 32 shuffles
__global__ void k_l1aggG(const uint2* __restrict__ rs2, const int* __restrict__ ss,
                         const float* __restrict__ sa, const float* __restrict__ dinv,
                         const float* __restrict__ Win, const float* __restrict__ bin,
                         const float* __restrict__ Wmid, unsigned char* __restrict__ Gh,
                         int N) {
    int t = blockIdx.x * blockDim.x + threadIdx.x;
    int i = t >> 5, l = t & 31;
    if (i >= N) return;
    float wcol[32];
    #pragma unroll
    for (int k = 0; k < 32; ++k) wcol[k] = Wmid[k * 32 + l];
    uint2 r = rs2[i];
    int beg = (int)r.x, end = (int)(r.x + r.y);
    float s = 0.f;
    for (int e = beg + l; e < end; e += 32) s += sa[ss[e]];
    #pragma unroll
    for (int m = 16; m; m >>= 1) s += __shfl_xor(s, m, 32);
    float d = dinv[i];
    float h = d * (s + sa[i]);
    float F = h * Win[l] + bin[l];
    F = F > 0.f ? F : 0.f;
    float g = 0.f;
    #pragma unroll
    for (int k = 0; k < 32; ++k) g += __shfl(F, k, 32) * wcol[k];
    float v = g * d * FP8_SCALE;
    Gh[t] = (unsigned char)(__builtin_amdgcn_cvt_pk_fp8_f32(v, v, 0, false) & 0xFF);
}

// accumulate one fp8x8 row-slice (uint2) into packed f32 accumulators
__device__ __forceinline__ void acc_row(f32x2* a2, uint2 v) {
    a2[0] += __builtin_amdgcn_cvt_pk_f32_fp8(v.x, false);
    a2[1] += __builtin_amdgcn_cvt_pk_f32_fp8(v.x, true);
    a2[2] += __builtin_amdgcn_cvt_pk_f32_fp8(v.y, false);
    a2[3] += __builtin_amdgcn_cvt_pk_f32_fp8(v.y, true);
}

// layer-2 aggregate + fused layer-3 matvec: branchless phantom-padded 8-deep
// fp8 gather -> f32 pk-accumulate -> relu F rows (LDS) -> block 32x32 matvec
// -> Gh3 (fp8)
__global__ void __launch_bounds__(256) k_agg2mv(
        const uint2* __restrict__ rs2, const int* __restrict__ ss,
        const uint2* __restrict__ G8, const float* __restrict__ dinv,
        const float* __restrict__ b, const float* __restrict__ Wmid,
        unsigned char* __restrict__ Gh3, int N) {
    __shared__ float sW[1024];
    __shared__ float sF[8][33];
    __shared__ float sdv[8];
    int t = threadIdx.x;
    #pragma unroll
    for (int r = 0; r < 4; ++r) sW[r * 256 + t] = Wmid[r * 256 + t];
    int tg = blockIdx.x * blockDim.x + t;
    int g = tg >> 5;
    int lane = t & 31, sub = lane >> 2, fl = lane & 3;
    int grp = t >> 5;
    bool act = (g < N);
    f32x2 a2[4];
    #pragma unroll
    for (int j = 0; j < 4; ++j) a2[j] = (f32x2)0.f;
    if (act) {
        uint2 r = rs2[g];
        int beg = (int)r.x;
        int end = beg + (int)r.y;
        // first 64 edges: unconditional 8-deep batch; invalid slots -> phantom
        int idx[8];
        #pragma unroll
        for (int rr = 0; rr < 8; ++rr) {
            int slot = beg + sub + 8 * rr;
            int ssv = ss[slot];               // always safe (ss +64 slack)
            idx[rr] = (slot < end) ? ssv : N; // N = zeroed phantom row
        }
        uint2 v[8];
        #pragma unroll
        for (int rr = 0; rr < 8; ++rr) v[rr] = G8[(long long)idx[rr] * 4 + fl];
        #pragma unroll
        for (int rr = 0; rr < 8; ++rr) acc_row(a2, v[rr]);
        if (sub == 0) acc_row(a2, G8[(long long)g * 4 + fl]);   // self term
        // rare deep-degree tail (deg > 64)
        for (int e = beg + 64 + sub; e < end; e += 8)
            acc_row(a2, G8[(long long)ss[e] * 4 + fl]);
    }
    float acc[8];
    #pragma unroll
    for (int j = 0; j < 8; ++j) acc[j] = a2[j >> 1][j & 1];
    #pragma unroll
    for (int j = 0; j < 8; ++j) {
        acc[j] += __shfl_xor(acc[j], 4);
        acc[j] += __shfl_xor(acc[j], 8);
        acc[j] += __shfl_xor(acc[j], 16);
    }
    if (act && sub == 0) {
        float d = dinv[g];
        if (fl == 0) sdv[grp] = d;
        float ds = d * FP8_INV;
        #pragma unroll
        for (int j = 0; j < 8; ++j) {
            float v = ds * acc[j] + b[fl * 8 + j];
            sF[grp][fl * 8 + j] = v > 0.f ? v : 0.f;
        }
    }
    __syncthreads();
    // block matvec: node grp, output feature lane
    if (act) {
        float s = 0.f;
        #pragma unroll
        for (int k = 0; k < 32; ++k) s += sF[grp][k] * sW[k * 32 + lane];
        float v = s * sdv[grp] * FP8_SCALE;
        Gh3[(long long)g * 32 + lane] =
            (unsigned char)(__builtin_amdgcn_cvt_pk_fp8_f32(v, v, 0, false) & 0xFF);
    }
}

// layer-3 aggregate + fused W_out dot: same gather structure; writes only sa[i]
__global__ void __launch_bounds__(256) k_agg3(
        const uint2* __restrict__ rs2, const int* __restrict__ ss,
        const uint2* __restrict__ G8, const float* __restrict__ dinv,
        const float* __restrict__ b, const float* __restrict__ Wout,
        float* __restrict__ sa, int N) {
    int t = blockIdx.x * blockDim.x + threadIdx.x;
    int g = t >> 5;
    if (g >= N) return;
    int lane = t & 31, sub = lane >> 2, fl = lane & 3;
    uint2 r = rs2[g];
    int beg = (int)r.x;
    int end = beg + (int)r.y;
    f32x2 a2[4];
    #pragma unroll
    for (int j = 0; j < 4; ++j) a2[j] = (f32x2)0.f;
    int idx[8];
    #pragma unroll
    for (int rr = 0; rr < 8; ++rr) {
        int slot = beg + sub + 8 * rr;
        int ssv = ss[slot];               // always safe (ss +64 slack)
        idx[rr] = (slot < end) ? ssv : N; // N = zeroed phantom row
    }
    uint2 v[8];
    #pragma unroll
    for (int rr = 0; rr < 8; ++rr) v[rr] = G8[(long long)idx[rr] * 4 + fl];
    #pragma unroll
    for (int rr = 0; rr < 8; ++rr) acc_row(a2, v[rr]);
    if (sub == 0) acc_row(a2, G8[(long long)g * 4 + fl]);   // self term
    for (int e = beg + 64 + sub; e < end; e += 8)
        acc_row(a2, G8[(long long)ss[e] * 4 + fl]);
    float acc[8];
    #pragma unroll
    for (int j = 0; j < 8; ++j) acc[j] = a2[j >> 1][j & 1];
    #pragma unroll
    for (int j = 0; j < 8; ++j) {
        acc[j] += __shfl_xor(acc[j], 4);
        acc[j] += __shfl_xor(acc[j], 8);
        acc[j] += __shfl_xor(acc[j], 16);
    }
    if (sub == 0) {
        float d = dinv[g];
        float ds = d * FP8_INV;
        float p = 0.f;
        #pragma unroll
        for (int j = 0; j < 8; ++j) {
            float v = ds * acc[j] + b[fl * 8 + j];
            v = v > 0.f ? v : 0.f;
            p += v * Wout[fl * 8 + j];
        }
        p += __shfl_xor(p, 1, 32);
        p += __shfl_xor(p, 2, 32);
        if (fl == 0) sa[g] = p * d;
    }
}

// layer 4: scalar gather-reduce + sigmoid, fused
__global__ void k_final_agg(const uint2* __restrict__ rs2, const int* __restrict__ ss,
                            const float* __restrict__ sa, const float* __restrict__ dinv,
                            const float* __restrict__ bout, float* __restrict__ out, int N) {
    int t = blockIdx.x * blockDim.x + threadIdx.x;
    int i = t >> 5, l = t & 31;
    if (i >= N) return;
    uint2 r = rs2[i];
    int beg = (int)r.x, end = (int)(r.x + r.y);
    float s = 0.f;
    for (int e = beg + l; e < end; e += 32) s += sa[ss[e]];
    #pragma unroll
    for (int m = 16; m; m >>= 1) s += __shfl_xor(s, m, 32);
    if (l == 0) {
        float z = dinv[i] * (s + sa[i]) + bout[0];
        out[i] = 1.0f / (1.0f + expf(-z));
    }
}

extern "C" void kernel_launch(void* const* d_in, const int* in_sizes, int n_in,
                              void* d_out, int out_size, void* d_ws, size_t ws_size,
                              hipStream_t stream) {
    const float* x    = (const float*)d_in[0];
    const int*   ei   = (const int*)  d_in[1];
    const float* Win  = (const float*)d_in[2];
    const float* bin  = (const float*)d_in[3];
    const float* Wmid = (const float*)d_in[4];
    const float* bmid = (const float*)d_in[5];
    const float* Wout = (const float*)d_in[6];
    const float* bout = (const float*)d_in[7];
    float* out = (float*)d_out;

    int N = in_sizes[0];
    int E = in_sizes[1] / 2;
    const int* src = ei;
    const int* dst = ei + E;

    int NB = (N + 127) >> 7;                       // 782 buckets of 128 nodes
    int chunk = (E + NBLK - 1) / NBLK;             // 12500

    // workspace layout (all regions disjoint; ~40MB)
    int* cursor = (int*)d_ws;                      // 1024
    uint2* rs2  = (uint2*)(cursor + 1024);         // N+8
    int* ss     = (int*)(rs2 + N + 8);             // NB*CAP + 64 slack
    float* dinv = (float*)(ss + (size_t)NB * CAP + 64); // N
    float* sa   = dinv + N;                        // N
    unsigned char* Gh  = (unsigned char*)(sa + N); // 32N + 32 (phantom) fp8
    unsigned char* Gh3 = Gh + 32 * (size_t)N + 32; // 32N + 32 fp8
    int* bkt    = (int*)(Gh3 + 32 * (size_t)N + 32); // NB*CAP

    int NT   = N * 32;
    int gN32 = (NT + BLK - 1) / BLK;

    // CSR build: init cursors + zero phantom rows -> LDS multisplit place ->
    // per-bucket sort
    k_initcur<<<(NB + BLK - 1) / BLK, BLK, 0, stream>>>(
        cursor, NB, (int*)(Gh + 32 * (size_t)N), (int*)(Gh3 + 32 * (size_t)N));
    k_place<<<NBLK, PBLK, 0, stream>>>(src, dst, cursor, bkt, E, chunk);
    k_build<<<NB, BBLK, 0, stream>>>(cursor, bkt, x, rs2, ss, dinv, sa, N);

    // layer 1 (+ fused layer-2 matvec) -> Gh (fp8)
    k_l1aggG<<<gN32, BLK, 0, stream>>>(rs2, ss, sa, dinv, Win, bin, Wmid, Gh, N);

    // layer 2 aggregate (+ fused layer-3 matvec) -> Gh3 (fp8)
    k_agg2mv<<<gN32, BLK, 0, stream>>>(rs2, ss, (const uint2*)Gh, dinv, bmid,
                                       Wmid, Gh3, N);

    // layer 3 aggregate (+ fused W_out dot) -> sa
    k_agg3<<<gN32, BLK, 0, stream>>>(rs2, ss, (const uint2*)Gh3, dinv, bmid,
                                     Wout, sa, N);

    // layer 4: scalar aggregate + sigmoid
    k_final_agg<<<gN32, BLK, 0, stream>>>(rs2, ss, sa, dinv, bout, out, N);
}